// Round 21
// baseline (114.679 us; speedup 1.0000x reference)
//
#include <hip/hip_runtime.h>
#include <math.h>
#include <float.h>
#include <limits.h>

#define NBATCH 4
#define NPROP  4096
#define NCLS   91
#define NFG    90
#define NDET   100
#define CCAP   1024            // per-(image,class) bucket cap (measured n ~ 80-350)
#define BN     (NBATCH * NPROP)
#define SLOTS  (NFG * NDET)    // 9000 survivor slots per image
#define CHUNK  128             // NMS matrix-walk chunk size
#define CPAD   32              // counter padding: 32 ints = 128 B per bucket counter

typedef unsigned long long ull;

static __device__ __forceinline__ float clampf(float x, float lo, float hi) {
    return fminf(fmaxf(x, lo), hi);
}

// Decode + clip one (proposal, class) box. Identical arithmetic everywhere it is
// used -> bitwise-identical results (validated absmax 0.0, R1-R20).
static __device__ __forceinline__ void decode_box(int b, int np, int c,
    const float* __restrict__ props, const float* __restrict__ deltas,
    float W, float H, float& bx1, float& by1, float& bx2, float& by2)
{
    const float* pr = props + ((size_t)b * NPROP + np) * 4;
    const float x1 = pr[0], y1 = pr[1], x2 = pr[2], y2 = pr[3];
    const float w = x2 - x1, h = y2 - y1;
    const float cx = x1 + 0.5f * w, cy = y1 + 0.5f * h;
    const float* d = deltas + (((size_t)b * NPROP + np) * NCLS + c) * 4;
    const float BBC = 4.135166556742356f;   // log(1000/16)
    const float dx = d[0] / 10.0f;
    const float dy = d[1] / 10.0f;
    const float dw = fminf(d[2] / 5.0f, BBC);
    const float dh = fminf(d[3] / 5.0f, BBC);
    const float pcx = dx * w + cx;
    const float pcy = dy * h + cy;
    const float pw = expf(dw) * w;
    const float ph = expf(dh) * h;
    bx1 = clampf(pcx - 0.5f * pw, 0.0f, W);
    by1 = clampf(pcy - 0.5f * ph, 0.0f, H);
    bx2 = clampf(pcx + 0.5f * pw, 0.0f, W);
    by2 = clampf(pcy + 0.5f * ph, 0.0f, H);
}

// IoU > 0.5 predicate, identical float expression to all validated rounds.
static __device__ __forceinline__ bool iou_gt(const float4 S, const float4 Q, float aq)
{
    const float iw = fmaxf(fminf(S.z, Q.z) - fmaxf(S.x, Q.x), 0.0f);
    const float ih = fmaxf(fminf(S.w, Q.w) - fmaxf(S.y, Q.y), 0.0f);
    const float inter = iw * ih;
    const float as = (S.z - S.x) * (S.w - S.y);
    return inter / (as + aq - inter) > 0.5f;
}

// Block-wide exclusive scan (256 threads = 4 waves; wtot = 4 ints of LDS).
static __device__ __forceinline__ int block_excl_scan(int v, int t, int* wtot)
{
    const int lane = t & 63, wid = t >> 6;
    int inc = v;
    #pragma unroll
    for (int s = 1; s < 64; s <<= 1) {
        const int u = __shfl_up(inc, s);
        if (lane >= s) inc += u;
    }
    if (lane == 63) wtot[wid] = inc;
    __syncthreads();
    int base = 0;
    for (int w2 = 0; w2 < wid; ++w2) base += wtot[w2];
    __syncthreads();                 // protect wtot for the next call
    return base + inc - v;
}

// Kernel 0: zero padded bucket counters + done[] flags (tail of cntPad alloc).
__global__ __launch_bounds__(256) void zero_kernel(int* __restrict__ cntPad)
{
    const int i = blockIdx.x * 256 + threadIdx.x;
    if (i < NBATCH * NFG * CPAD + 256) cntPad[i] = 0;
}

// Kernel 1 (FUSED): softmax + filter + decode + direct bucket write.
// Byte-identical to validated R19/R20.
__global__ __launch_bounds__(256) void fused_decode_kernel(
    const float* __restrict__ logits, const float* __restrict__ props,
    const float* __restrict__ deltas, const int* __restrict__ imgsh,
    int* __restrict__ cntPad, ull* __restrict__ cKeys, float4* __restrict__ cBox)
{
    const int wavei = threadIdx.x >> 6;
    const int lane  = threadIdx.x & 63;
    const int p = blockIdx.x * 4 + wavei;          // 0 .. B*N-1
    const int b = p >> 12;
    const int np = p & (NPROP - 1);
    const float* lrow = logits + (size_t)p * NCLS;

    const float a  = lrow[lane];
    const float a2 = (lane + 64 < NCLS) ? lrow[lane + 64] : -INFINITY;

    float m = fmaxf(a, a2);                        // level s=64
    #pragma unroll
    for (int s = 32; s > 0; s >>= 1) m = fmaxf(m, __shfl_down(m, s));
    m = __shfl(m, 0);

    const float e0 = expf(a - m);
    const float e1 = (lane + 64 < NCLS) ? expf(a2 - m) : 0.0f;
    float sum = e0 + e1;                           // level s=64
    #pragma unroll
    for (int s = 32; s > 0; s >>= 1) sum += __shfl_down(sum, s);
    sum = __shfl(sum, 0);

    const float W = (float)imgsh[b * 2 + 1];
    const float H = (float)imgsh[b * 2 + 0];

    #pragma unroll
    for (int half = 0; half < 2; ++half) {
        const int c = lane + half * 64;            // class index
        if (c < 1 || c >= NCLS) continue;
        const float e = half ? e1 : e0;
        const float score = e / sum;               // bitwise = validated expr
        if (!(score > 0.05f)) continue;
        float bx1, by1, bx2, by2;
        decode_box(b, np, c, props, deltas, W, H, bx1, by1, bx2, by2);
        if (!((bx2 - bx1) >= 0.01f && (by2 - by1) >= 0.01f)) continue;
        const int cm1 = c - 1;
        const unsigned flat = (unsigned)(np * NFG + cm1);
        const ull key = ((ull)__float_as_uint(score) << 32) | (unsigned)(~flat);
        const int bucket = b * NFG + cm1;
        const int pos = atomicAdd(&cntPad[bucket * CPAD], 1);  // own 128B line
        if (pos < CCAP) {
            cKeys[(size_t)bucket * CCAP + pos] = key;
            cBox[(size_t)bucket * CCAP + pos]  = make_float4(bx1, by1, bx2, by2);
        }
    }
}

// Kernel 2 (FUSED NMS+SELECT): one block (256 thr) per (image,class) runs the
// R19/R20-validated NMS; the LAST block to finish per image (device-scope
// fence + atomic done-counter) runs radix top-100 select inline. Select output
// is a pure function of svKeys content -> deterministic regardless of which
// block executes it. LDS is a carved union (NMS 36.4 KB / select 33.6 KB).
__global__ __launch_bounds__(256) void nms_select_kernel(
    const int* __restrict__ cntPad, const ull* __restrict__ cKeys,
    const float4* __restrict__ cBox, ull* __restrict__ svKeys,
    int* __restrict__ done,
    const float* __restrict__ props, const float* __restrict__ deltas,
    const int* __restrict__ imgsh, float* __restrict__ out)
{
    const int blk  = blockIdx.x;                   // 0..359
    const int b    = blk / NFG;
    const int t    = threadIdx.x;
    const int lane = t & 63, wid = t >> 6;

    __shared__ __align__(16) ull smem[4608];       // 36.9 KB, carved per phase
    __shared__ int s_ns, s_last, s_T, s_above, s_total, wtot[4];
    __shared__ ull s_best;

    // ---------------- NMS phase (validated logic) ----------------
    {
        ull* sk       = smem;                      // [0,1024)
        ull* sks      = smem + 1024;               // [1024,2048)
        float4* sboxS = (float4*)(smem + 2048);    // 1024 float4 -> [2048,4096)
        ull (*mrow)[2] = (ull (*)[2])(smem + 4096);// [4096,4352)
        float4* sOwn  = (float4*)(smem + 4352);    // 100 float4 -> [4352,4552)
        ull* sPreW    = smem + 4552;               // [4552,4554)

        const int n = min(cntPad[blk * CPAD], CCAP);
        if (n == 0) {
            for (int i = t; i < NDET; i += 256) svKeys[(size_t)blk * NDET + i] = 0ULL;
        } else {
            const ull* srcK = cKeys + (size_t)blk * CCAP;
            const float4* srcB = cBox + (size_t)blk * CCAP;
            for (int i = t; i < n; i += 256) sk[i] = srcK[i];
            __syncthreads();

            // rank-by-counting sort (desc), carrying boxes; unique keys
            {
                ull myk[4]; float4 myb[4]; int rnk[4] = {0, 0, 0, 0};
                #pragma unroll
                for (int e = 0; e < 4; ++e) {
                    const int i = t + e * 256;
                    myk[e] = (i < n) ? sk[i] : 0ULL;
                    myb[e] = (i < n) ? srcB[i] : make_float4(0.f, 0.f, 0.f, 0.f);
                }
                #pragma unroll 4
                for (int j = 0; j < n; ++j) {
                    const ull kj = sk[j];
                    #pragma unroll
                    for (int e = 0; e < 4; ++e) rnk[e] += (kj > myk[e]) ? 1 : 0;
                }
                #pragma unroll
                for (int e = 0; e < 4; ++e)
                    if (t + e * 256 < n) { sks[rnk[e]] = myk[e]; sboxS[rnk[e]] = myb[e]; }
            }
            if (t == 0) s_ns = 0;
            __syncthreads();

            // chunked suppression-matrix greedy NMS (R14-validated)
            int nsTot = 0;
            for (int cb = 0; cb < n && nsTot < NDET; cb += CHUNK) {
                const int C = min(CHUNK, n - cb);
                bool pre = false;
                if (t < C) {
                    const float4 Q = sboxS[cb + t];
                    const float aq = (Q.z - Q.x) * (Q.w - Q.y);
                    for (int l = 0; l < nsTot; ++l)
                        if (iou_gt(sOwn[l], Q, aq)) { pre = true; break; }
                }
                const ull bal = __ballot(pre);
                if (t == 0)  sPreW[0] = bal;
                if (t == 64) sPreW[1] = bal;
                {
                    const int r = t >> 1, w = t & 1;
                    ull word = 0ULL;
                    if (r < C) {
                        const float4 R = sboxS[cb + r];
                        const int j0 = w * 64;
                        const int jend = min(j0 + 64, C);
                        for (int j = (j0 > r + 1 ? j0 : r + 1); j < jend; ++j) {
                            const float4 Q = sboxS[cb + j];
                            const float aq = (Q.z - Q.x) * (Q.w - Q.y);
                            if (iou_gt(R, Q, aq)) word |= (1ULL << (j - j0));
                        }
                    }
                    mrow[r][w] = word;
                }
                __syncthreads();
                if (t == 0) {
                    ull S0 = sPreW[0], S1 = sPreW[1];
                    int ns = nsTot;
                    ull r0 = mrow[0][0], r1 = mrow[0][1];
                    for (int i = 0; i < C && ns < NDET; ++i) {
                        const ull nr0 = (i + 1 < C) ? mrow[i + 1][0] : 0ULL;
                        const ull nr1 = (i + 1 < C) ? mrow[i + 1][1] : 0ULL;
                        const bool dead = (i < 64) ? ((S0 >> i) & 1ULL)
                                                   : ((S1 >> (i - 64)) & 1ULL);
                        if (!dead) {
                            sOwn[ns] = sboxS[cb + i];
                            svKeys[(size_t)blk * NDET + ns] = sks[cb + i];
                            ++ns;
                            S0 |= r0; S1 |= r1;
                        }
                        r0 = nr0; r1 = nr1;
                    }
                    s_ns = ns;
                }
                __syncthreads();
                nsTot = s_ns;
            }
            for (int i = nsTot + t; i < NDET; i += 256) svKeys[(size_t)blk * NDET + i] = 0ULL;
        }
    }

    // ---------------- completion: last block per image selects ----------------
    __syncthreads();
    __threadfence();                               // release svKeys (device scope)
    if (t == 0) {
        s_last = (atomicAdd(&done[b], 1) == NFG - 1) ? 1 : 0;
        s_T = -1; s_above = 0; s_total = 0;        // init select state
    }
    __syncthreads();
    if (!s_last) return;
    __threadfence();                               // acquire

    // ---------------- SELECT phase (radix top-100, 256 threads) ----------------
    ull* F      = smem;                            // [0,2048) keys (16 KB)
    int* hist   = (int*)(smem + 2048);             // 4096 ints
    ull* chosen = smem + 4096;                     // [4096,4196)
    ull* wred   = smem + 4196;                     // [4196,4200)

    for (int i = t; i < 4096; i += 256) hist[i] = 0;
    for (int i = t; i < NDET; i += 256) chosen[i] = 0ULL;
    __syncthreads();

    const ull* src = svKeys + (size_t)b * SLOTS;
    for (int s = t; s < SLOTS; s += 256) {
        const ull k = src[s];
        if (k) atomicAdd(&hist[(unsigned)(k >> 52)], 1);
    }
    __syncthreads();

    {
        const int gbase = (255 - t) * 16;          // thread 0 owns HIGHEST buckets
        int s0 = 0;
        #pragma unroll
        for (int j = 0; j < 16; ++j) s0 += hist[gbase + j];
        const int pre = block_excl_scan(s0, t, wtot);  // counts in higher buckets
        int acc = pre;
        for (int d = gbase + 15; d >= gbase; --d) {
            const int h = hist[d];
            if (acc < NDET && acc + h >= NDET) { s_T = d; s_above = acc; }  // unique writer
            acc += h;
        }
        if (t == 255) s_total = acc;
    }
    __syncthreads();

    const int T = s_T, total = s_total;
    const int n2 = (T < 0) ? total : (s_above + hist[T]);

    if (n2 <= 2048) {
        // deterministic compaction of {digit >= T} (superset of top-100)
        int mycnt = 0;
        for (int s = t; s < SLOTS; s += 256) {
            const ull k = src[s];
            if (k && (T < 0 || (int)(k >> 52) >= T)) ++mycnt;
        }
        int off = block_excl_scan(mycnt, t, wtot);
        for (int s = t; s < SLOTS; s += 256) {
            const ull k = src[s];
            if (k && (T < 0 || (int)(k >> 52) >= T)) F[off++] = k;
        }
        __syncthreads();
        // rank-sort: unique keys -> bijective ranks; only ranks < NDET emitted
        ull myk[8]; int rnk[8];
        #pragma unroll
        for (int e = 0; e < 8; ++e) {
            const int i = t + e * 256;
            myk[e] = (i < n2) ? F[i] : 0ULL;
            rnk[e] = 0;
        }
        for (int j = 0; j < n2; ++j) {
            const ull kj = F[j];
            #pragma unroll
            for (int e = 0; e < 8; ++e) rnk[e] += (kj > myk[e]) ? 1 : 0;
        }
        __syncthreads();
        #pragma unroll
        for (int e = 0; e < 8; ++e) {
            const int i = t + e * 256;
            if (i < n2 && rnk[e] < NDET) chosen[rnk[e]] = myk[e];
        }
        __syncthreads();
    } else {
        // guaranteed-correct fallback (unreachable for real score data):
        // 100 rounds of bounded argmax over svKeys (L2-hot), strictly descending.
        ull ub = ~0ULL;                            // keys never equal ~0 (score<=1)
        for (int r = 0; r < NDET; ++r) {
            ull best = 0ULL;
            for (int s = t; s < SLOTS; s += 256) {
                const ull k = src[s];
                if (k < ub && k > best) best = k;
            }
            #pragma unroll
            for (int o = 32; o > 0; o >>= 1) {
                const ull ob = __shfl_down(best, o);
                if (ob > best) best = ob;
            }
            if (lane == 0) wred[wid] = best;
            __syncthreads();
            if (t == 0) {
                ull mx = wred[0];
                for (int w2 = 1; w2 < 4; ++w2) if (wred[w2] > mx) mx = wred[w2];
                s_best = mx;
                if (mx) chosen[r] = mx;
            }
            __syncthreads();
            if (s_best == 0ULL) break;             // uniform
            ub = s_best;
            __syncthreads();                       // protect wred reuse
        }
    }

    // ---------------- decode outputs (validated epilogue) ----------------
    float* oB = out + (size_t)b * NDET * 4;
    float* oS = out + (size_t)NBATCH * NDET * 4 + (size_t)b * NDET;
    float* oL = out + (size_t)NBATCH * NDET * 5 + (size_t)b * NDET;
    if (t < NDET) {
        const ull key = chosen[t];
        if (key != 0ULL) {
            const unsigned flat = ~(unsigned)key;
            const float score = __uint_as_float((unsigned)(key >> 32));
            const int np = flat / NFG;
            const int c  = (int)(flat - (unsigned)np * NFG) + 1;
            const float W = (float)imgsh[b * 2 + 1];
            const float H = (float)imgsh[b * 2 + 0];
            float bx1, by1, bx2, by2;
            decode_box(b, np, c, props, deltas, W, H, bx1, by1, bx2, by2);
            oB[t * 4 + 0] = bx1; oB[t * 4 + 1] = by1;
            oB[t * 4 + 2] = bx2; oB[t * 4 + 3] = by2;
            oS[t] = score;
            oL[t] = (float)c;
        } else {
            oB[t * 4 + 0] = 0.0f; oB[t * 4 + 1] = 0.0f;
            oB[t * 4 + 2] = 0.0f; oB[t * 4 + 3] = 0.0f;
            oS[t] = 0.0f; oL[t] = -1.0f;
        }
    }
}

extern "C" void kernel_launch(void* const* d_in, const int* in_sizes, int n_in,
                              void* d_out, int out_size, void* d_ws, size_t ws_size,
                              hipStream_t stream)
{
    const float* logits = (const float*)d_in[0];   // [B*N, 91]
    const float* deltas = (const float*)d_in[1];   // [B*N, 364]
    const float* props  = (const float*)d_in[2];   // [B, N, 4]
    const int*   imgsh  = (const int*)d_in[3];     // [B, 2]
    float* out = (float*)d_out;

    char* w = (char*)d_ws;
    int* cntPad = (int*)w;                 // counters + done[] tail
    w += (size_t)(NBATCH * NFG * CPAD + 256) * sizeof(int);                        // 47 KB
    ull* svKeys = (ull*)w;
    w += (size_t)NBATCH * SLOTS * sizeof(ull);                                     // 288 KB
    ull* cKeys = (ull*)w;
    w += (size_t)NBATCH * NFG * CCAP * sizeof(ull);                                // 2.95 MB
    float4* cBox = (float4*)w;
    w += (size_t)NBATCH * NFG * CCAP * sizeof(float4);                             // 5.9 MB

    int* done = cntPad + NBATCH * NFG * CPAD;

    const int nz = (NBATCH * NFG * CPAD + 256 + 255) / 256;
    zero_kernel<<<nz, 256, 0, stream>>>(cntPad);
    fused_decode_kernel<<<BN / 4, 256, 0, stream>>>(
        logits, props, deltas, imgsh, cntPad, cKeys, cBox);
    nms_select_kernel<<<NBATCH * NFG, 256, 0, stream>>>(
        cntPad, cKeys, cBox, svKeys, done, props, deltas, imgsh, out);
}